// Round 1
// baseline (487.528 us; speedup 1.0000x reference)
//
#include <hip/hip_runtime.h>
#include <hip/hip_bf16.h>

#define NHEADS 6
#define HDIM 32
#define NTOK 64
#define QK_LD 40   // q/k LDS row stride (shorts): 80B, 16B-aligned, 2-way-free banks
#define VT_LD 72   // vt/p LDS row stride (shorts): 144B, 16B-aligned
#define P_LD 72

typedef short short8v __attribute__((ext_vector_type(8)));
typedef short short4v __attribute__((ext_vector_type(4)));
typedef float float4v __attribute__((ext_vector_type(4)));

__device__ __forceinline__ short f2bf(float f) {
    union { __hip_bfloat16 h; short s; } u;
    u.h = __float2bfloat16(f);   // RTNE
    return u.s;
}

// ---- bias[h][n][m] = (relu(rel_pos @ w1 + b1) @ w2 + b2), h-major ----
__global__ void bias_mlp_kernel(const float* __restrict__ rel_pos,
                                const float* __restrict__ w1,
                                const float* __restrict__ b1,
                                const float* __restrict__ w2,
                                const float* __restrict__ b2,
                                float* __restrict__ bias) {
    int idx = blockIdx.x * blockDim.x + threadIdx.x;  // n*64+m, 0..4095
    float r0 = rel_pos[idx * 2 + 0];
    float r1 = rel_pos[idx * 2 + 1];
    float acc[NHEADS];
#pragma unroll
    for (int h = 0; h < NHEADS; ++h) acc[h] = b2[h];
    for (int j = 0; j < 256; ++j) {
        float hv = fmaf(r0, w1[j], fmaf(r1, w1[256 + j], b1[j]));
        hv = fmaxf(hv, 0.0f);
#pragma unroll
        for (int h = 0; h < NHEADS; ++h)
            acc[h] = fmaf(hv, w2[j * NHEADS + h], acc[h]);
    }
#pragma unroll
    for (int h = 0; h < NHEADS; ++h)
        bias[h * 4096 + idx] = acc[h];
}

// ---- fused window attention: one block = (window, head-pair), 4 waves ----
// wave = (local head, row half). LDS 48128B -> 3 blocks/CU.
__global__ __launch_bounds__(256, 3)
void attn_kernel(const float* __restrict__ qkv,
                 const float* __restrict__ bias,
                 float* __restrict__ out) {
    __shared__ short s_q[2][NTOK][QK_LD];    // q * SCALE, bf16
    __shared__ short s_k[2][NTOK][QK_LD];
    __shared__ short s_vt[2][HDIM][VT_LD];   // V transposed: [d][m]
    __shared__ short s_p[2][NTOK][P_LD];     // unnormalized softmax probs

    const int tid = threadIdx.x;
    const int b = blockIdx.x;
    const int h0 = blockIdx.y * 2;
    const float* base = qkv + (size_t)b * (NTOK * 576);

    // stage this window's 2 heads: 64 rows x 192 floats = 3072 float4
#pragma unroll
    for (int it = 0; it < 12; ++it) {
        int idx = tid + it * 256;           // 0..3071
        int row = idx / 48;
        int cc = idx - row * 48;            // 0..47
        int chunk = cc >> 3;                // 0..5: q0 q1 k0 k1 v0 v1
        int part = chunk >> 1;
        int hsel = chunk & 1;
        int d = (cc & 7) * 4;
        float4v v4 = *(const float4v*)(base + row * 576 + part * 192 + (h0 + hsel) * 32 + d);
        if (part == 0) {
            const float s = 0.17677669529663687f;  // 32^-0.5 folded into q
            short4v pk;
            pk.x = f2bf(v4.x * s); pk.y = f2bf(v4.y * s);
            pk.z = f2bf(v4.z * s); pk.w = f2bf(v4.w * s);
            *(short4v*)&s_q[hsel][row][d] = pk;
        } else if (part == 1) {
            short4v pk;
            pk.x = f2bf(v4.x); pk.y = f2bf(v4.y);
            pk.z = f2bf(v4.z); pk.w = f2bf(v4.w);
            *(short4v*)&s_k[hsel][row][d] = pk;
        } else {
            s_vt[hsel][d + 0][row] = f2bf(v4.x);
            s_vt[hsel][d + 1][row] = f2bf(v4.y);
            s_vt[hsel][d + 2][row] = f2bf(v4.z);
            s_vt[hsel][d + 3][row] = f2bf(v4.w);
        }
    }
    __syncthreads();

    const int wid = tid >> 6;
    const int lane = tid & 63;
    const int hl = wid >> 1;          // local head 0/1
    const int half = wid & 1;         // which 32 S-rows this wave owns
    const int c = lane & 15;
    const int quad = lane >> 4;
    const int rbase = half * 32;

    // S = Q K^T: A-frag = q rows, B-frag = k rows (B^T layout), K=32 in one mfma
    short8v aq[2], bk[4];
#pragma unroll
    for (int i = 0; i < 2; ++i)
        aq[i] = *(const short8v*)&s_q[hl][rbase + i * 16 + c][quad * 8];
#pragma unroll
    for (int j = 0; j < 4; ++j)
        bk[j] = *(const short8v*)&s_k[hl][j * 16 + c][quad * 8];

    float4v S[2][4];
#pragma unroll
    for (int i = 0; i < 2; ++i)
#pragma unroll
        for (int j = 0; j < 4; ++j) {
            float4v z = {0.f, 0.f, 0.f, 0.f};
            S[i][j] = __builtin_amdgcn_mfma_f32_16x16x32_bf16(aq[i], bk[j], z, 0, 0, 0);
        }

    // softmax over each row (C-layout: col=lane&15, row=quad*4+r); bias added fp32
    const float* bh = bias + (h0 + hl) * 4096;
    float rs[2][4];
#pragma unroll
    for (int i = 0; i < 2; ++i) {
#pragma unroll
        for (int r = 0; r < 4; ++r) {
            int row = rbase + i * 16 + quad * 4 + r;
            const float* brow = bh + row * 64 + c;
            float l0 = S[i][0][r] + brow[0];
            float l1 = S[i][1][r] + brow[16];
            float l2 = S[i][2][r] + brow[32];
            float l3 = S[i][3][r] + brow[48];
            float m = fmaxf(fmaxf(l0, l1), fmaxf(l2, l3));
#pragma unroll
            for (int off = 1; off < 16; off <<= 1)
                m = fmaxf(m, __shfl_xor(m, off, 64));
            l0 = __expf(l0 - m); l1 = __expf(l1 - m);
            l2 = __expf(l2 - m); l3 = __expf(l3 - m);
            float sum = l0 + l1 + l2 + l3;
#pragma unroll
            for (int off = 1; off < 16; off <<= 1)
                sum += __shfl_xor(sum, off, 64);
            rs[i][r] = 1.0f / sum;           // normalize in epilogue instead
            s_p[hl][row][c]      = f2bf(l0);
            s_p[hl][row][c + 16] = f2bf(l1);
            s_p[hl][row][c + 32] = f2bf(l2);
            s_p[hl][row][c + 48] = f2bf(l3);
        }
    }

    // O = P V: A-frag from own P rows (same-wave LDS roundtrip), B-frag from V^T
    short8v bv[2][2], pa[2][2];
#pragma unroll
    for (int t = 0; t < 2; ++t)
#pragma unroll
        for (int kk = 0; kk < 2; ++kk)
            bv[t][kk] = *(const short8v*)&s_vt[hl][t * 16 + c][kk * 32 + quad * 8];
#pragma unroll
    for (int i = 0; i < 2; ++i)
#pragma unroll
        for (int kk = 0; kk < 2; ++kk)
            pa[i][kk] = *(const short8v*)&s_p[hl][rbase + i * 16 + c][kk * 32 + quad * 8];

    float4v O[2][2];
#pragma unroll
    for (int i = 0; i < 2; ++i)
#pragma unroll
        for (int t = 0; t < 2; ++t) {
            float4v z = {0.f, 0.f, 0.f, 0.f};
            z = __builtin_amdgcn_mfma_f32_16x16x32_bf16(pa[i][0], bv[t][0], z, 0, 0, 0);
            O[i][t] = __builtin_amdgcn_mfma_f32_16x16x32_bf16(pa[i][1], bv[t][1], z, 0, 0, 0);
        }

    // epilogue: O rows in C-layout match the rows this lane owned in softmax
    float* ob = out + (size_t)b * (NTOK * 192) + (h0 + hl) * 32;
#pragma unroll
    for (int i = 0; i < 2; ++i)
#pragma unroll
        for (int t = 0; t < 2; ++t)
#pragma unroll
            for (int r = 0; r < 4; ++r) {
                int row = rbase + i * 16 + quad * 4 + r;
                ob[row * 192 + t * 16 + c] = O[i][t][r] * rs[i][r];
            }
}

extern "C" void kernel_launch(void* const* d_in, const int* in_sizes, int n_in,
                              void* d_out, int out_size, void* d_ws, size_t ws_size,
                              hipStream_t stream) {
    const float* qkv     = (const float*)d_in[0];
    const float* rel_pos = (const float*)d_in[1];
    const float* w1      = (const float*)d_in[2];
    const float* b1      = (const float*)d_in[3];
    const float* w2      = (const float*)d_in[4];
    const float* b2      = (const float*)d_in[5];
    float* bias = (float*)d_ws;      // 6*64*64 fp32 = 98304 B
    float* out  = (float*)d_out;

    bias_mlp_kernel<<<dim3(64), dim3(64), 0, stream>>>(rel_pos, w1, b1, w2, b2, bias);
    attn_kernel<<<dim3(2048, 3), dim3(256), 0, stream>>>(qkv, bias, out);
}

// Round 2
// 478.948 us; speedup vs baseline: 1.0179x; 1.0179x over previous
//
#include <hip/hip_runtime.h>
#include <hip/hip_bf16.h>

#define NHEADS 6
#define NTOK 64
#define QK_LD 40   // q/k LDS row stride (shorts): 80B, 16B-aligned
#define VT_LD 72   // vt LDS row stride (shorts): 144B, 16B-aligned
#define P_LD 72

typedef short short8v __attribute__((ext_vector_type(8)));
typedef short short4v __attribute__((ext_vector_type(4)));
typedef float float4v __attribute__((ext_vector_type(4)));

__device__ __forceinline__ short f2bf(float f) {
    union { __hip_bfloat16 h; short s; } u;
    u.h = __float2bfloat16(f);   // RTNE
    return u.s;
}

// ---- bias[h][n][m] = (relu(rel_pos @ w1 + b1) @ w2 + b2), h-major ----
__global__ void bias_mlp_kernel(const float* __restrict__ rel_pos,
                                const float* __restrict__ w1,
                                const float* __restrict__ b1,
                                const float* __restrict__ w2,
                                const float* __restrict__ b2,
                                float* __restrict__ bias) {
    int idx = blockIdx.x * blockDim.x + threadIdx.x;  // n*64+m, 0..4095
    float r0 = rel_pos[idx * 2 + 0];
    float r1 = rel_pos[idx * 2 + 1];
    float acc[NHEADS];
#pragma unroll
    for (int h = 0; h < NHEADS; ++h) acc[h] = b2[h];
    for (int j = 0; j < 256; ++j) {
        float hv = fmaf(r0, w1[j], fmaf(r1, w1[256 + j], b1[j]));
        hv = fmaxf(hv, 0.0f);
#pragma unroll
        for (int h = 0; h < NHEADS; ++h)
            acc[h] = fmaf(hv, w2[j * NHEADS + h], acc[h]);
    }
#pragma unroll
    for (int h = 0; h < NHEADS; ++h)
        bias[h * 4096 + idx] = acc[h];
}

// ---- fused window attention: one block = (window, head-pair), 4 waves ----
// LDS 29696B (s_p overlays s_q/s_k) -> 4+ blocks/CU.
// S computed TRANSPOSED (T = K * Q^T) so softmax reduces in-lane over 16 regs
// + 2 cross-quad shuffles instead of 8 cross-lane shuffles per row.
__global__ __launch_bounds__(256, 4)
void attn_kernel(const float* __restrict__ qkv,
                 const float* __restrict__ bias,
                 float* __restrict__ out) {
    __shared__ __align__(16) char s_qkp[20480];        // q(10240) | k(10240); p overlays
    __shared__ __align__(16) short s_vt[2][32][VT_LD]; // V^T: [head][d][tok], 9216B
    short (*s_q)[NTOK][QK_LD] = (short (*)[NTOK][QK_LD])(s_qkp);
    short (*s_k)[NTOK][QK_LD] = (short (*)[NTOK][QK_LD])(s_qkp + 10240);
    short (*s_p)[NTOK][P_LD]  = (short (*)[NTOK][P_LD])(s_qkp);  // overlay, post-barrier

    const int tid = threadIdx.x;
    const int b = blockIdx.x;
    const int h0 = blockIdx.y * 2;
    const float* base = qkv + (size_t)b * (NTOK * 576);

    // stage this window's 2 heads: 64 rows x 192 floats = 3072 float4
#pragma unroll
    for (int it = 0; it < 12; ++it) {
        int idx = tid + it * 256;           // 0..3071
        int row = idx / 48;
        int cc = idx - row * 48;            // 0..47
        int chunk = cc >> 3;                // 0..5: q0 q1 k0 k1 v0 v1
        int part = chunk >> 1;
        int hsel = chunk & 1;
        int d = (cc & 7) * 4;
        float4v v4 = *(const float4v*)(base + row * 576 + part * 192 + (h0 + hsel) * 32 + d);
        if (part == 0) {
            const float s = 0.17677669529663687f;  // 32^-0.5 folded into q
            short4v pk = { f2bf(v4.x * s), f2bf(v4.y * s), f2bf(v4.z * s), f2bf(v4.w * s) };
            *(short4v*)&s_q[hsel][row][d] = pk;
        } else if (part == 1) {
            short4v pk = { f2bf(v4.x), f2bf(v4.y), f2bf(v4.z), f2bf(v4.w) };
            *(short4v*)&s_k[hsel][row][d] = pk;
        } else {
            s_vt[hsel][d + 0][row] = f2bf(v4.x);
            s_vt[hsel][d + 1][row] = f2bf(v4.y);
            s_vt[hsel][d + 2][row] = f2bf(v4.z);
            s_vt[hsel][d + 3][row] = f2bf(v4.w);
        }
    }
    __syncthreads();

    const int wid = tid >> 6;
    const int lane = tid & 63;
    const int hl = wid >> 1;          // local head 0/1
    const int half = wid & 1;         // which 32 q-rows this wave owns
    const int c = lane & 15;
    const int quad = lane >> 4;
    const int rbase = half * 32;

    short8v aq[2], bk[4];
#pragma unroll
    for (int i = 0; i < 2; ++i)
        aq[i] = *(const short8v*)&s_q[hl][rbase + i * 16 + c][quad * 8];
#pragma unroll
    for (int j = 0; j < 4; ++j)
        bk[j] = *(const short8v*)&s_k[hl][j * 16 + c][quad * 8];

    // T = K * Q^T (= S^T). C-layout: col(lane&15)=q-within-tile, row(quad*4+r)=k-within-tile
    float4v T[4][2];
#pragma unroll
    for (int j = 0; j < 4; ++j)
#pragma unroll
        for (int i = 0; i < 2; ++i) {
            float4v z = {0.f, 0.f, 0.f, 0.f};
            T[j][i] = __builtin_amdgcn_mfma_f32_16x16x32_bf16(bk[j], aq[i], z, 0, 0, 0);
        }

    __syncthreads();   // all q/k frag reads done before s_p overlays them

    // softmax per q-row: lane holds 16 k-values (4 tiles x 4 regs) of q-row rbase+16i+c
    const float* bh = bias + (h0 + hl) * 4096;
#pragma unroll
    for (int i = 0; i < 2; ++i) {
        const int qrow = rbase + i * 16 + c;
        float L[4][4];
        float m = -1e30f;
#pragma unroll
        for (int j = 0; j < 4; ++j) {
            float4v bb = *(const float4v*)(bh + qrow * 64 + j * 16 + quad * 4);
#pragma unroll
            for (int r = 0; r < 4; ++r) {
                L[j][r] = T[j][i][r] + bb[r];
                m = fmaxf(m, L[j][r]);
            }
        }
        m = fmaxf(m, __shfl_xor(m, 16, 64));
        m = fmaxf(m, __shfl_xor(m, 32, 64));
        float sum = 0.f;
#pragma unroll
        for (int j = 0; j < 4; ++j)
#pragma unroll
            for (int r = 0; r < 4; ++r) {
                L[j][r] = __expf(L[j][r] - m);
                sum += L[j][r];
            }
        sum += __shfl_xor(sum, 16, 64);
        sum += __shfl_xor(sum, 32, 64);
        float inv = 1.0f / sum;     // normalize P here; epilogue needs no rescale
#pragma unroll
        for (int j = 0; j < 4; ++j) {
            short4v pk = { f2bf(L[j][0] * inv), f2bf(L[j][1] * inv),
                           f2bf(L[j][2] * inv), f2bf(L[j][3] * inv) };
            *(short4v*)&s_p[hl][qrow][j * 16 + quad * 4] = pk;
        }
    }

    // O = P * V: A-frags from own P rows (same-wave LDS), B-frags from V^T
    short8v bv[2][2], pa[2][2];
#pragma unroll
    for (int t = 0; t < 2; ++t)
#pragma unroll
        for (int kk = 0; kk < 2; ++kk)
            bv[t][kk] = *(const short8v*)&s_vt[hl][t * 16 + c][kk * 32 + quad * 8];
#pragma unroll
    for (int i = 0; i < 2; ++i)
#pragma unroll
        for (int kk = 0; kk < 2; ++kk)
            pa[i][kk] = *(const short8v*)&s_p[hl][rbase + i * 16 + c][kk * 32 + quad * 8];

    float4v O[2][2];
#pragma unroll
    for (int i = 0; i < 2; ++i)
#pragma unroll
        for (int t = 0; t < 2; ++t) {
            float4v z = {0.f, 0.f, 0.f, 0.f};
            z = __builtin_amdgcn_mfma_f32_16x16x32_bf16(pa[i][0], bv[t][0], z, 0, 0, 0);
            O[i][t] = __builtin_amdgcn_mfma_f32_16x16x32_bf16(pa[i][1], bv[t][1], z, 0, 0, 0);
        }

    // epilogue: C-layout row = q-row, col = d; P already normalized
    float* ob = out + (size_t)b * (NTOK * 192) + (h0 + hl) * 32;
#pragma unroll
    for (int i = 0; i < 2; ++i)
#pragma unroll
        for (int t = 0; t < 2; ++t)
#pragma unroll
            for (int r = 0; r < 4; ++r) {
                int row = rbase + i * 16 + quad * 4 + r;
                ob[row * 192 + t * 16 + c] = O[i][t][r];
            }
}

extern "C" void kernel_launch(void* const* d_in, const int* in_sizes, int n_in,
                              void* d_out, int out_size, void* d_ws, size_t ws_size,
                              hipStream_t stream) {
    const float* qkv     = (const float*)d_in[0];
    const float* rel_pos = (const float*)d_in[1];
    const float* w1      = (const float*)d_in[2];
    const float* b1      = (const float*)d_in[3];
    const float* w2      = (const float*)d_in[4];
    const float* b2      = (const float*)d_in[5];
    float* bias = (float*)d_ws;      // 6*64*64 fp32 = 98304 B
    float* out  = (float*)d_out;

    bias_mlp_kernel<<<dim3(64), dim3(64), 0, stream>>>(rel_pos, w1, b1, w2, b2, bias);
    attn_kernel<<<dim3(2048, 3), dim3(256), 0, stream>>>(qkv, bias, out);
}